// Round 19
// baseline (151.630 us; speedup 1.0000x reference)
//
#include <hip/hip_runtime.h>
#include <hip/hip_fp16.h>

namespace {
constexpr int Bn = 2, Cin = 64, Cout = 64;
constexpr int Dd = 8, Hh = 48, Wd = 48;
constexpr int K = 27;
constexpr int SP = Dd * Hh * Wd;   // 18432
constexpr int PLANE = Hh * Wd;     // 2304
constexpr int NT32 = SP / 32;      // 576 32-pos tiles per batch
constexpr int KC = 9;              // K-split factor (main GEMM); KPER = 3
constexpr int KPER = K / KC;
constexpr int CS = 2;              // cin-split factor (offset conv)
constexpr int TS = 2;              // tap-split factor (offset conv)
}

typedef __attribute__((ext_vector_type(8))) _Float16 half8;
typedef __attribute__((ext_vector_type(4))) float f32x4;
typedef __attribute__((ext_vector_type(16))) float f32x16;

__device__ __forceinline__ unsigned short f2h(float f) {  // RNE float->f16 bits
  return __half_as_ushort(__float2half(f));
}
__device__ __forceinline__ __half2 u2h2(unsigned u) {
  return __builtin_bit_cast(__half2, u);
}
__device__ __forceinline__ unsigned h22u(__half2 h) {
  return __builtin_bit_cast(unsigned, h);
}

// Fused prep: xTh (channels-last f16 x), wTb (main-W A-frag layout),
// wq (offset-W 32x32-MFMA A-frag layout).
__global__ __launch_bounds__(256) void k_prep(const float* __restrict__ x,
                                              const float* __restrict__ w,
                                              const float* __restrict__ cw,
                                              unsigned short* __restrict__ xTh,
                                              unsigned short* __restrict__ wTb,
                                              unsigned short* __restrict__ wq) {
  int i = blockIdx.x * 256 + threadIdx.x;   // 2,635,776 total
  if (i < 2359296) {
    int c = i & 63;
    int rest = i >> 6;
    int p = rest % SP;
    int b = rest / SP;
    xTh[i] = f2h(x[(b * Cin + c) * SP + p]);
  } else if (i < 2359296 + 110592) {
    int i2 = i - 2359296;
    int j = i2 & 7, kg = (i2 >> 3) & 3, row = (i2 >> 5) & 15;
    int s = (i2 >> 9) & 1, mt = (i2 >> 10) & 3, k = i2 >> 12;
    int co = mt * 16 + row, cin = s * 32 + kg * 8 + j;
    wTb[i2] = f2h(w[((size_t)co * Cin + cin) * K + k]);
  } else {
    // wq[tap][cs(2)][kh(2)][mt(3)][row(32)][ko(2)][j(8)]
    int i3 = i - 2469888;                   // < 165,888
    int j = i3 & 7, ko = (i3 >> 3) & 1, row = (i3 >> 4) & 31;
    int qq = i3 >> 9;
    int mt = qq % 3;
    int rest = qq / 3;
    int kh = rest & 1;
    int cs = (rest >> 1) & 1;
    int tap = rest >> 2;
    int ch = mt * 32 + row, cin = cs * 32 + kh * 16 + ko * 8 + j;
    float v = (ch < 81) ? cw[((size_t)ch * 64 + cin) * 27 + tap] : 0.f;
    wq[i3] = f2h(v);
  }
}

// Offset conv via 32x32x16 MFMA (validated R18).
__global__ __launch_bounds__(256, 4) void k_offm3(const unsigned short* __restrict__ xTh,
                                                  const unsigned short* __restrict__ wq,
                                                  unsigned short* __restrict__ opart) {
  const int t = threadIdx.x;
  const int lane = t & 63;
  const int wv = t >> 6;                   // 0..3
  const int bid = blockIdx.x;              // slice*288 + nb ; 1152 total
  const int slice = bid / 288;             // ts*2 + cs
  const int nb = bid - slice * 288;
  const int ts = slice >> 1;
  const int cs = slice & 1;
  const int n0 = nb * 128;
  const int b = n0 / SP;
  const int sp0 = n0 - b * SP;

  const int col = lane & 31;
  const int ko = lane >> 5;
  const int q = sp0 + wv * 32 + col;
  const int d = q / PLANE;
  const int rp = q - d * PLANE;
  const int h = rp / 48;
  const int w = rp - h * 48;
  const int grow = b * SP + q;

  const char* xb8 = (const char*)xTh;
  const unsigned short* wbase = wq + cs * 3072 + col * 16 + ko * 8;
  const int bofs = cs * 64 + ko * 16;

  f32x16 acc[3];
#pragma unroll
  for (int mt = 0; mt < 3; ++mt)
#pragma unroll
    for (int r = 0; r < 16; ++r) acc[mt][r] = 0.f;

  const int t0 = ts * 14;
#pragma unroll
  for (int tt = 0; tt < 14; ++tt) {
    const int tap = t0 + tt;
    const bool tok = tap < 27;
    const int tap_c = tok ? tap : 26;
    const int kd = tap_c / 9, kh3 = (tap_c % 9) / 3, kw = tap_c % 3;
    const int dd = d + kd - 1, hh = h + kh3 - 1, ww = w + kw - 1;
    const bool valid = tok & ((unsigned)dd < 8u) & ((unsigned)hh < 48u) &
                       ((unsigned)ww < 48u);
    const int delta = (kd - 1) * PLANE + (kh3 - 1) * 48 + (kw - 1);
    int row = grow + delta;
    row = min(max(row, 0), Bn * SP - 1);
    const char* bp = xb8 + ((size_t)row << 7) + bofs;
    uint4 b0 = *reinterpret_cast<const uint4*>(bp);
    uint4 b1 = *reinterpret_cast<const uint4*>(bp + 32);
    const unsigned m = valid ? 0xFFFFFFFFu : 0u;
    b0.x &= m; b0.y &= m; b0.z &= m; b0.w &= m;
    b1.x &= m; b1.y &= m; b1.z &= m; b1.w &= m;
    half8 bf0 = __builtin_bit_cast(half8, b0);
    half8 bf1 = __builtin_bit_cast(half8, b1);
    const unsigned short* wt = wbase + tap_c * 6144;
#pragma unroll
    for (int mt = 0; mt < 3; ++mt) {
      half8 a0 = *reinterpret_cast<const half8*>(wt + mt * 512);
      acc[mt] = __builtin_amdgcn_mfma_f32_32x32x16_f16(a0, bf0, acc[mt], 0, 0, 0);
    }
#pragma unroll
    for (int mt = 0; mt < 3; ++mt) {
      half8 a1 = *reinterpret_cast<const half8*>(wt + 1536 + mt * 512);
      acc[mt] = __builtin_amdgcn_mfma_f32_32x32x16_f16(a1, bf1, acc[mt], 0, 0, 0);
    }
  }

  const int colp = sp0 + wv * 32 + col;
  unsigned short* pp = opart + (size_t)(slice * 2 + b) * 81 * SP;
#pragma unroll
  for (int mt = 0; mt < 3; ++mt) {
#pragma unroll
    for (int reg = 0; reg < 16; ++reg) {
      int ch = mt * 32 + (reg & 3) + 8 * (reg >> 2) + 4 * ko;
      if (ch < 81)
        pp[(size_t)ch * SP + colp] = f2h(acc[mt][reg]);
    }
  }
}

// offT[b][k][p] = float4(pd, ph, pw, 0), base grid + conv bias folded in;
// sums 4 f16 opart slices.
__global__ __launch_bounds__(256) void k_offT(const unsigned short* __restrict__ opart,
                                              const float* __restrict__ cb,
                                              float* __restrict__ offT) {
  int i = blockIdx.x * 256 + threadIdx.x;  // 2*27*4608 = 248,832
  int p4 = i % (SP / 4);
  int k = (i / (SP / 4)) % 27;
  int b = i / ((SP / 4) * 27);
  int kd = k / 9, kh = (k % 9) / 3, kw = k % 3;

  const __half2* op2 = (const __half2*)opart;
  float s[3][4];
#pragma unroll
  for (int dim = 0; dim < 3; ++dim) {
    int ch = dim * 27 + k;
    float bb = cb[ch];
    s[dim][0] = bb; s[dim][1] = bb; s[dim][2] = bb; s[dim][3] = bb;
#pragma unroll
    for (int sl = 0; sl < 4; ++sl) {
      size_t e0 = (((size_t)((sl * 2 + b) * 81 + ch)) * SP + p4 * 4) >> 1;
      float2 a0 = __half22float2(op2[e0]);
      float2 a1 = __half22float2(op2[e0 + 1]);
      s[dim][0] += a0.x; s[dim][1] += a0.y; s[dim][2] += a1.x; s[dim][3] += a1.y;
    }
  }
  float4* o4 = (float4*)offT + ((size_t)(b * 27 + k) * SP + p4 * 4);
#pragma unroll
  for (int e = 0; e < 4; ++e) {
    int p = p4 * 4 + e;
    int d = p / PLANE;
    int r = p - d * PLANE;
    int h = r / 48;
    int wp = r - h * 48;
    o4[e] = float4{s[0][e] + (float)(d + kd - 1), s[1][e] + (float)(h + kh - 1),
                   s[2][e] + (float)(wp + kw - 1), 0.f};
  }
}

// Fused gather + MFMA GEMM (R14 structure; f16 part). KC=9: 10368 blocks x
// 2 waves = 81 waves/CU available -> occupancy saturates at 32/CU (was 27).
__global__ __launch_bounds__(128, 8) void k_mainp(const unsigned short* __restrict__ xTh,
                                                  const float* __restrict__ offT,
                                                  const unsigned short* __restrict__ wTb,
                                                  unsigned short* __restrict__ part) {
  __shared__ __align__(16) unsigned scp[2][16 * 20];         // per-wave [pos16][20w]
  __shared__ __align__(16) unsigned short vals[2][16 * 72];  // per-wave [pos16][cin]

  const int t = threadIdx.x;
  const int lane = t & 63;
  const int wv = t >> 6;                         // 0..1
  const int bid = blockIdx.x;                    // kc*1152 + j
  const int kc = bid / 1152;
  const int j = bid - kc * 1152;
  const int tl = (j & 7) * 144 + (j >> 3);       // XCD-contiguous tiles
  const int b = tl / NT32;
  const int tile = tl - b * NT32;
  const int p0 = tile * 32;

  const char* xb8 = (const char*)(xTh + (size_t)b * SP * 64);
  const float4* offTb = (const float4*)offT + (size_t)b * 27 * SP;

  const int posl = lane & 15;
  const int quad = lane >> 4;
  const int p = p0 + wv * 16 + posl;             // this lane's position
  unsigned* myrow = &scp[wv][posl * 20];

  const int gpl0 = lane >> 3;   // gather: row base 0..7
  const int gchg = lane & 7;    // gather: 8-channel chunk

  f32x4 acc[4];
#pragma unroll
  for (int mt = 0; mt < 4; ++mt) acc[mt] = f32x4{0.f, 0.f, 0.f, 0.f};

  for (int kk = 0; kk < KPER; ++kk) {
    const int k = kc * KPER + kk;
    // ---- setup: corners 2*quad, 2*quad+1 of position p (offT pre-folded)
    {
      float4 o = offTb[(size_t)k * SP + p];
      float df = floorf(o.x), hf = floorf(o.y), wf = floorf(o.z);
      float fd = o.x - df, fh = o.y - hf, fw = o.z - wf;
      int d0 = (int)df, h0 = (int)hf, w0i = (int)wf;
      unsigned pk[4];
#pragma unroll
      for (int cc = 0; cc < 2; ++cc) {
        int c = quad * 2 + cc;
        int cd = c >> 2, ch = (c >> 1) & 1, cwb = c & 1;
        int di = d0 + cd, hi = h0 + ch, wi = w0i + cwb;
        bool v = ((unsigned)di < 8u) && ((unsigned)hi < 48u) && ((unsigned)wi < 48u);
        float wg = (cd ? fd : 1.f - fd) * (ch ? fh : 1.f - fh) * (cwb ? fw : 1.f - fw);
        int dic = min(max(di, 0), 7), hic = min(max(hi, 0), 47), wic = min(max(wi, 0), 47);
        unsigned hs = (unsigned)f2h(v ? wg : 0.f);
        pk[cc * 2] = (unsigned)((dic * 48 + hic) * 48 + wic);
        pk[cc * 2 + 1] = hs | (hs << 16);
      }
      *reinterpret_cast<uint4*>(myrow + quad * 4) = uint4{pk[0], pk[1], pk[2], pk[3]};
    }
    // ---- gather: 2 units/lane, rows gpl0 and gpl0+8 (same-wave LDS ordering)
#pragma unroll
    for (int u = 0; u < 2; ++u) {
      const int pl = gpl0 + u * 8;
      const unsigned* sp = &scp[wv][pl * 20];
      const uint4 m0 = *reinterpret_cast<const uint4*>(sp + 0);
      const uint4 m1 = *reinterpret_cast<const uint4*>(sp + 4);
      const uint4 m2 = *reinterpret_cast<const uint4*>(sp + 8);
      const uint4 m3 = *reinterpret_cast<const uint4*>(sp + 12);
      const int cof = gchg << 4;
      uint4 q0 = *reinterpret_cast<const uint4*>(xb8 + (((size_t)m0.x << 7) + cof));
      uint4 q1 = *reinterpret_cast<const uint4*>(xb8 + (((size_t)m0.z << 7) + cof));
      uint4 q2 = *reinterpret_cast<const uint4*>(xb8 + (((size_t)m1.x << 7) + cof));
      uint4 q3 = *reinterpret_cast<const uint4*>(xb8 + (((size_t)m1.z << 7) + cof));
      uint4 q4 = *reinterpret_cast<const uint4*>(xb8 + (((size_t)m2.x << 7) + cof));
      uint4 q5 = *reinterpret_cast<const uint4*>(xb8 + (((size_t)m2.z << 7) + cof));
      uint4 q6 = *reinterpret_cast<const uint4*>(xb8 + (((size_t)m3.x << 7) + cof));
      uint4 q7 = *reinterpret_cast<const uint4*>(xb8 + (((size_t)m3.z << 7) + cof));
      __half2 a2[4];
#pragma unroll
      for (int e = 0; e < 4; ++e) a2[e] = u2h2(0u);
      __half2 w0 = u2h2(m0.y), w1 = u2h2(m0.w), w2 = u2h2(m1.y), w3 = u2h2(m1.w);
      __half2 w4 = u2h2(m2.y), w5 = u2h2(m2.w), w6 = u2h2(m3.y), w7 = u2h2(m3.w);
      a2[0] = __hfma2(u2h2(q0.x), w0, a2[0]); a2[1] = __hfma2(u2h2(q0.y), w0, a2[1]);
      a2[2] = __hfma2(u2h2(q0.z), w0, a2[2]); a2[3] = __hfma2(u2h2(q0.w), w0, a2[3]);
      a2[0] = __hfma2(u2h2(q1.x), w1, a2[0]); a2[1] = __hfma2(u2h2(q1.y), w1, a2[1]);
      a2[2] = __hfma2(u2h2(q1.z), w1, a2[2]); a2[3] = __hfma2(u2h2(q1.w), w1, a2[3]);
      a2[0] = __hfma2(u2h2(q2.x), w2, a2[0]); a2[1] = __hfma2(u2h2(q2.y), w2, a2[1]);
      a2[2] = __hfma2(u2h2(q2.z), w2, a2[2]); a2[3] = __hfma2(u2h2(q2.w), w2, a2[3]);
      a2[0] = __hfma2(u2h2(q3.x), w3, a2[0]); a2[1] = __hfma2(u2h2(q3.y), w3, a2[1]);
      a2[2] = __hfma2(u2h2(q3.z), w3, a2[2]); a2[3] = __hfma2(u2h2(q3.w), w3, a2[3]);
      a2[0] = __hfma2(u2h2(q4.x), w4, a2[0]); a2[1] = __hfma2(u2h2(q4.y), w4, a2[1]);
      a2[2] = __hfma2(u2h2(q4.z), w4, a2[2]); a2[3] = __hfma2(u2h2(q4.w), w4, a2[3]);
      a2[0] = __hfma2(u2h2(q5.x), w5, a2[0]); a2[1] = __hfma2(u2h2(q5.y), w5, a2[1]);
      a2[2] = __hfma2(u2h2(q5.z), w5, a2[2]); a2[3] = __hfma2(u2h2(q5.w), w5, a2[3]);
      a2[0] = __hfma2(u2h2(q6.x), w6, a2[0]); a2[1] = __hfma2(u2h2(q6.y), w6, a2[1]);
      a2[2] = __hfma2(u2h2(q6.z), w6, a2[2]); a2[3] = __hfma2(u2h2(q6.w), w6, a2[3]);
      a2[0] = __hfma2(u2h2(q7.x), w7, a2[0]); a2[1] = __hfma2(u2h2(q7.y), w7, a2[1]);
      a2[2] = __hfma2(u2h2(q7.z), w7, a2[2]); a2[3] = __hfma2(u2h2(q7.w), w7, a2[3]);
      *reinterpret_cast<uint4*>(&vals[wv][pl * 72 + gchg * 8]) =
          uint4{h22u(a2[0]), h22u(a2[1]), h22u(a2[2]), h22u(a2[3])};
    }
    // ---- MFMA: B-frag from this wave's own vals (same-wave ordering)
    {
      const unsigned short* wk = wTb + (size_t)k * 4096;
#pragma unroll
      for (int s = 0; s < 2; ++s) {
        half8 bfr = *reinterpret_cast<const half8*>(
            &vals[wv][posl * 72 + s * 32 + quad * 8]);
#pragma unroll
        for (int mt = 0; mt < 4; ++mt) {
          half8 afr = *reinterpret_cast<const half8*>(
              wk + mt * 1024 + s * 512 + posl * 32 + quad * 8);
          acc[mt] = __builtin_amdgcn_mfma_f32_16x16x32_f16(afr, bfr, acc[mt], 0, 0, 0);
        }
      }
    }
  }

  // part[kc][b][tile32][co][32] f16; co = mt*16+quad*4+reg, pos = wv*16+posl
  unsigned short* pp = part + ((size_t)(kc * 2 + b) * NT32 + tile) * 2048;
#pragma unroll
  for (int mt = 0; mt < 4; ++mt) {
#pragma unroll
    for (int reg = 0; reg < 4; ++reg) {
      int co = mt * 16 + quad * 4 + reg;
      pp[co * 32 + wv * 16 + posl] = f2h(acc[mt][reg]);
    }
  }
}

// out[b][co][p] = bias[co] + sum_kc part[kc][b][tile32][co][pos]  (f16 in, f32 out)
__global__ __launch_bounds__(256) void k_red(const unsigned short* __restrict__ part,
                                             const float* __restrict__ bias,
                                             float* __restrict__ out) {
  int i = blockIdx.x * 256 + threadIdx.x;  // 589,824 float4 units
  int p4 = i % (SP / 4);
  int co = (i / (SP / 4)) & 63;
  int b = i / ((SP / 4) * 64);
  int p = p4 * 4;
  int tile = p >> 5, pos = p & 31;
  size_t base = ((size_t)(b * NT32) + tile) * 2048 + co * 32 + pos;
  const __half2* h2 = (const __half2*)part;
  float bb = bias[co];
  float4 s = float4{bb, bb, bb, bb};
#pragma unroll
  for (int kc = 0; kc < KC; ++kc) {
    size_t e = (base + (size_t)kc * 2 * NT32 * 2048) >> 1;
    float2 a = __half22float2(h2[e]);
    float2 c = __half22float2(h2[e + 1]);
    s.x += a.x; s.y += a.y; s.z += c.x; s.w += c.y;
  }
  *reinterpret_cast<float4*>(&out[((size_t)(b * 64 + co)) * SP + p]) = s;
}

extern "C" void kernel_launch(void* const* d_in, const int* in_sizes, int n_in,
                              void* d_out, int out_size, void* d_ws, size_t ws_size,
                              hipStream_t stream) {
  const float* x = (const float*)d_in[0];
  const float* cw = (const float*)d_in[1];
  const float* cb = (const float*)d_in[2];
  const float* w = (const float*)d_in[3];
  const float* bias = (const float*)d_in[4];
  float* out = (float*)d_out;

  char* ws = (char*)d_ws;
  float* offT = (float*)ws;                                  // 15,925,248 B
  unsigned short* xTh = (unsigned short*)(ws + 15925248);    //  4,718,592 B
  unsigned short* wTb = (unsigned short*)(ws + 20643840);    //    221,184 B
  unsigned short* wq = (unsigned short*)(ws + 20865024);     //    331,776 B
  unsigned short* part = (unsigned short*)(ws + 21196800);   // 42,467,328 B (f16, 9 slices)
  unsigned short* opart = (unsigned short*)(ws + 63664128);  // 23,887,872 B (f16, 4 slices)

  hipLaunchKernelGGL(k_prep, dim3(10296), dim3(256), 0, stream, x, w, cw, xTh, wTb, wq);
  hipLaunchKernelGGL(k_offm3, dim3(TS * CS * 288), dim3(256), 0, stream, xTh, wq, opart);
  hipLaunchKernelGGL(k_offT, dim3(972), dim3(256), 0, stream, opart, cb, offT);
  hipLaunchKernelGGL(k_mainp, dim3(KC * 1152), dim3(128), 0, stream, xTh, offT, wTb, part);
  hipLaunchKernelGGL(k_red, dim3(2304), dim3(256), 0, stream, part, bias, out);
}

// Round 20
// 136.754 us; speedup vs baseline: 1.1088x; 1.1088x over previous
//
#include <hip/hip_runtime.h>
#include <hip/hip_fp16.h>

namespace {
constexpr int Bn = 2, Cin = 64, Cout = 64;
constexpr int Dd = 8, Hh = 48, Wd = 48;
constexpr int K = 27;
constexpr int SP = Dd * Hh * Wd;   // 18432
constexpr int PLANE = Hh * Wd;     // 2304
constexpr int NT32 = SP / 32;      // 576 32-pos tiles per batch
constexpr int KC = 3;              // K-split factor (main GEMM); KPER = 9
constexpr int KPER = K / KC;
constexpr int CS = 2;              // cin-split factor (offset conv)
constexpr int TS = 2;              // tap-split factor (offset conv)
}

typedef __attribute__((ext_vector_type(8))) _Float16 half8;
typedef __attribute__((ext_vector_type(4))) float f32x4;
typedef __attribute__((ext_vector_type(16))) float f32x16;

__device__ __forceinline__ unsigned short f2h(float f) {  // RNE float->f16 bits
  return __half_as_ushort(__float2half(f));
}
__device__ __forceinline__ __half2 u2h2(unsigned u) {
  return __builtin_bit_cast(__half2, u);
}
__device__ __forceinline__ unsigned h22u(__half2 h) {
  return __builtin_bit_cast(unsigned, h);
}

// Fused prep: xTh (channels-last f16 x), wTb (main-W A-frag layout),
// wq (offset-W 32x32-MFMA A-frag layout).
__global__ __launch_bounds__(256) void k_prep(const float* __restrict__ x,
                                              const float* __restrict__ w,
                                              const float* __restrict__ cw,
                                              unsigned short* __restrict__ xTh,
                                              unsigned short* __restrict__ wTb,
                                              unsigned short* __restrict__ wq) {
  int i = blockIdx.x * 256 + threadIdx.x;   // 2,635,776 total
  if (i < 2359296) {
    int c = i & 63;
    int rest = i >> 6;
    int p = rest % SP;
    int b = rest / SP;
    xTh[i] = f2h(x[(b * Cin + c) * SP + p]);
  } else if (i < 2359296 + 110592) {
    int i2 = i - 2359296;
    int j = i2 & 7, kg = (i2 >> 3) & 3, row = (i2 >> 5) & 15;
    int s = (i2 >> 9) & 1, mt = (i2 >> 10) & 3, k = i2 >> 12;
    int co = mt * 16 + row, cin = s * 32 + kg * 8 + j;
    wTb[i2] = f2h(w[((size_t)co * Cin + cin) * K + k]);
  } else {
    // wq[tap][cs(2)][kh(2)][mt(3)][row(32)][ko(2)][j(8)]
    int i3 = i - 2469888;                   // < 165,888
    int j = i3 & 7, ko = (i3 >> 3) & 1, row = (i3 >> 4) & 31;
    int qq = i3 >> 9;
    int mt = qq % 3;
    int rest = qq / 3;
    int kh = rest & 1;
    int cs = (rest >> 1) & 1;
    int tap = rest >> 2;
    int ch = mt * 32 + row, cin = cs * 32 + kh * 16 + ko * 8 + j;
    float v = (ch < 81) ? cw[((size_t)ch * 64 + cin) * 27 + tap] : 0.f;
    wq[i3] = f2h(v);
  }
}

// Offset conv via 32x32x16 MFMA (validated R18).
__global__ __launch_bounds__(256, 4) void k_offm3(const unsigned short* __restrict__ xTh,
                                                  const unsigned short* __restrict__ wq,
                                                  unsigned short* __restrict__ opart) {
  const int t = threadIdx.x;
  const int lane = t & 63;
  const int wv = t >> 6;                   // 0..3
  const int bid = blockIdx.x;              // slice*288 + nb ; 1152 total
  const int slice = bid / 288;             // ts*2 + cs
  const int nb = bid - slice * 288;
  const int ts = slice >> 1;
  const int cs = slice & 1;
  const int n0 = nb * 128;
  const int b = n0 / SP;
  const int sp0 = n0 - b * SP;

  const int col = lane & 31;
  const int ko = lane >> 5;
  const int q = sp0 + wv * 32 + col;
  const int d = q / PLANE;
  const int rp = q - d * PLANE;
  const int h = rp / 48;
  const int w = rp - h * 48;
  const int grow = b * SP + q;

  const char* xb8 = (const char*)xTh;
  const unsigned short* wbase = wq + cs * 3072 + col * 16 + ko * 8;
  const int bofs = cs * 64 + ko * 16;

  f32x16 acc[3];
#pragma unroll
  for (int mt = 0; mt < 3; ++mt)
#pragma unroll
    for (int r = 0; r < 16; ++r) acc[mt][r] = 0.f;

  const int t0 = ts * 14;
#pragma unroll
  for (int tt = 0; tt < 14; ++tt) {
    const int tap = t0 + tt;
    const bool tok = tap < 27;
    const int tap_c = tok ? tap : 26;
    const int kd = tap_c / 9, kh3 = (tap_c % 9) / 3, kw = tap_c % 3;
    const int dd = d + kd - 1, hh = h + kh3 - 1, ww = w + kw - 1;
    const bool valid = tok & ((unsigned)dd < 8u) & ((unsigned)hh < 48u) &
                       ((unsigned)ww < 48u);
    const int delta = (kd - 1) * PLANE + (kh3 - 1) * 48 + (kw - 1);
    int row = grow + delta;
    row = min(max(row, 0), Bn * SP - 1);
    const char* bp = xb8 + ((size_t)row << 7) + bofs;
    uint4 b0 = *reinterpret_cast<const uint4*>(bp);
    uint4 b1 = *reinterpret_cast<const uint4*>(bp + 32);
    const unsigned m = valid ? 0xFFFFFFFFu : 0u;
    b0.x &= m; b0.y &= m; b0.z &= m; b0.w &= m;
    b1.x &= m; b1.y &= m; b1.z &= m; b1.w &= m;
    half8 bf0 = __builtin_bit_cast(half8, b0);
    half8 bf1 = __builtin_bit_cast(half8, b1);
    const unsigned short* wt = wbase + tap_c * 6144;
#pragma unroll
    for (int mt = 0; mt < 3; ++mt) {
      half8 a0 = *reinterpret_cast<const half8*>(wt + mt * 512);
      acc[mt] = __builtin_amdgcn_mfma_f32_32x32x16_f16(a0, bf0, acc[mt], 0, 0, 0);
    }
#pragma unroll
    for (int mt = 0; mt < 3; ++mt) {
      half8 a1 = *reinterpret_cast<const half8*>(wt + 1536 + mt * 512);
      acc[mt] = __builtin_amdgcn_mfma_f32_32x32x16_f16(a1, bf1, acc[mt], 0, 0, 0);
    }
  }

  const int colp = sp0 + wv * 32 + col;
  unsigned short* pp = opart + (size_t)(slice * 2 + b) * 81 * SP;
#pragma unroll
  for (int mt = 0; mt < 3; ++mt) {
#pragma unroll
    for (int reg = 0; reg < 16; ++reg) {
      int ch = mt * 32 + (reg & 3) + 8 * (reg >> 2) + 4 * ko;
      if (ch < 81)
        pp[(size_t)ch * SP + colp] = f2h(acc[mt][reg]);
    }
  }
}

// offT[b][k][p] = float4(pd, ph, pw, 0), base grid + conv bias folded in;
// sums 4 f16 opart slices.
__global__ __launch_bounds__(256) void k_offT(const unsigned short* __restrict__ opart,
                                              const float* __restrict__ cb,
                                              float* __restrict__ offT) {
  int i = blockIdx.x * 256 + threadIdx.x;  // 2*27*4608 = 248,832
  int p4 = i % (SP / 4);
  int k = (i / (SP / 4)) % 27;
  int b = i / ((SP / 4) * 27);
  int kd = k / 9, kh = (k % 9) / 3, kw = k % 3;

  const __half2* op2 = (const __half2*)opart;
  float s[3][4];
#pragma unroll
  for (int dim = 0; dim < 3; ++dim) {
    int ch = dim * 27 + k;
    float bb = cb[ch];
    s[dim][0] = bb; s[dim][1] = bb; s[dim][2] = bb; s[dim][3] = bb;
#pragma unroll
    for (int sl = 0; sl < 4; ++sl) {
      size_t e0 = (((size_t)((sl * 2 + b) * 81 + ch)) * SP + p4 * 4) >> 1;
      float2 a0 = __half22float2(op2[e0]);
      float2 a1 = __half22float2(op2[e0 + 1]);
      s[dim][0] += a0.x; s[dim][1] += a0.y; s[dim][2] += a1.x; s[dim][3] += a1.y;
    }
  }
  float4* o4 = (float4*)offT + ((size_t)(b * 27 + k) * SP + p4 * 4);
#pragma unroll
  for (int e = 0; e < 4; ++e) {
    int p = p4 * 4 + e;
    int d = p / PLANE;
    int r = p - d * PLANE;
    int h = r / 48;
    int wp = r - h * 48;
    o4[e] = float4{s[0][e] + (float)(d + kd - 1), s[1][e] + (float)(h + kh - 1),
                   s[2][e] + (float)(wp + kw - 1), 0.f};
  }
}

// Fused gather + MFMA GEMM (R14 structure; f16 part; KC=3 — best measured).
__global__ __launch_bounds__(128, 8) void k_mainp(const unsigned short* __restrict__ xTh,
                                                  const float* __restrict__ offT,
                                                  const unsigned short* __restrict__ wTb,
                                                  unsigned short* __restrict__ part) {
  __shared__ __align__(16) unsigned scp[2][16 * 20];         // per-wave [pos16][20w]
  __shared__ __align__(16) unsigned short vals[2][16 * 72];  // per-wave [pos16][cin]

  const int t = threadIdx.x;
  const int lane = t & 63;
  const int wv = t >> 6;                         // 0..1
  const int bid = blockIdx.x;                    // kc*1152 + j
  const int kc = bid / 1152;
  const int j = bid - kc * 1152;
  const int tl = (j & 7) * 144 + (j >> 3);       // XCD-contiguous tiles
  const int b = tl / NT32;
  const int tile = tl - b * NT32;
  const int p0 = tile * 32;

  const char* xb8 = (const char*)(xTh + (size_t)b * SP * 64);
  const float4* offTb = (const float4*)offT + (size_t)b * 27 * SP;

  const int posl = lane & 15;
  const int quad = lane >> 4;
  const int p = p0 + wv * 16 + posl;             // this lane's position
  unsigned* myrow = &scp[wv][posl * 20];

  const int gpl0 = lane >> 3;   // gather: row base 0..7
  const int gchg = lane & 7;    // gather: 8-channel chunk

  f32x4 acc[4];
#pragma unroll
  for (int mt = 0; mt < 4; ++mt) acc[mt] = f32x4{0.f, 0.f, 0.f, 0.f};

  for (int kk = 0; kk < KPER; ++kk) {
    const int k = kc * KPER + kk;
    // ---- setup: corners 2*quad, 2*quad+1 of position p (offT pre-folded)
    {
      float4 o = offTb[(size_t)k * SP + p];
      float df = floorf(o.x), hf = floorf(o.y), wf = floorf(o.z);
      float fd = o.x - df, fh = o.y - hf, fw = o.z - wf;
      int d0 = (int)df, h0 = (int)hf, w0i = (int)wf;
      unsigned pk[4];
#pragma unroll
      for (int cc = 0; cc < 2; ++cc) {
        int c = quad * 2 + cc;
        int cd = c >> 2, ch = (c >> 1) & 1, cwb = c & 1;
        int di = d0 + cd, hi = h0 + ch, wi = w0i + cwb;
        bool v = ((unsigned)di < 8u) && ((unsigned)hi < 48u) && ((unsigned)wi < 48u);
        float wg = (cd ? fd : 1.f - fd) * (ch ? fh : 1.f - fh) * (cwb ? fw : 1.f - fw);
        int dic = min(max(di, 0), 7), hic = min(max(hi, 0), 47), wic = min(max(wi, 0), 47);
        unsigned hs = (unsigned)f2h(v ? wg : 0.f);
        pk[cc * 2] = (unsigned)((dic * 48 + hic) * 48 + wic);
        pk[cc * 2 + 1] = hs | (hs << 16);
      }
      *reinterpret_cast<uint4*>(myrow + quad * 4) = uint4{pk[0], pk[1], pk[2], pk[3]};
    }
    // ---- gather: 2 units/lane, rows gpl0 and gpl0+8 (same-wave LDS ordering)
#pragma unroll
    for (int u = 0; u < 2; ++u) {
      const int pl = gpl0 + u * 8;
      const unsigned* sp = &scp[wv][pl * 20];
      const uint4 m0 = *reinterpret_cast<const uint4*>(sp + 0);
      const uint4 m1 = *reinterpret_cast<const uint4*>(sp + 4);
      const uint4 m2 = *reinterpret_cast<const uint4*>(sp + 8);
      const uint4 m3 = *reinterpret_cast<const uint4*>(sp + 12);
      const int cof = gchg << 4;
      uint4 q0 = *reinterpret_cast<const uint4*>(xb8 + (((size_t)m0.x << 7) + cof));
      uint4 q1 = *reinterpret_cast<const uint4*>(xb8 + (((size_t)m0.z << 7) + cof));
      uint4 q2 = *reinterpret_cast<const uint4*>(xb8 + (((size_t)m1.x << 7) + cof));
      uint4 q3 = *reinterpret_cast<const uint4*>(xb8 + (((size_t)m1.z << 7) + cof));
      uint4 q4 = *reinterpret_cast<const uint4*>(xb8 + (((size_t)m2.x << 7) + cof));
      uint4 q5 = *reinterpret_cast<const uint4*>(xb8 + (((size_t)m2.z << 7) + cof));
      uint4 q6 = *reinterpret_cast<const uint4*>(xb8 + (((size_t)m3.x << 7) + cof));
      uint4 q7 = *reinterpret_cast<const uint4*>(xb8 + (((size_t)m3.z << 7) + cof));
      __half2 a2[4];
#pragma unroll
      for (int e = 0; e < 4; ++e) a2[e] = u2h2(0u);
      __half2 w0 = u2h2(m0.y), w1 = u2h2(m0.w), w2 = u2h2(m1.y), w3 = u2h2(m1.w);
      __half2 w4 = u2h2(m2.y), w5 = u2h2(m2.w), w6 = u2h2(m3.y), w7 = u2h2(m3.w);
      a2[0] = __hfma2(u2h2(q0.x), w0, a2[0]); a2[1] = __hfma2(u2h2(q0.y), w0, a2[1]);
      a2[2] = __hfma2(u2h2(q0.z), w0, a2[2]); a2[3] = __hfma2(u2h2(q0.w), w0, a2[3]);
      a2[0] = __hfma2(u2h2(q1.x), w1, a2[0]); a2[1] = __hfma2(u2h2(q1.y), w1, a2[1]);
      a2[2] = __hfma2(u2h2(q1.z), w1, a2[2]); a2[3] = __hfma2(u2h2(q1.w), w1, a2[3]);
      a2[0] = __hfma2(u2h2(q2.x), w2, a2[0]); a2[1] = __hfma2(u2h2(q2.y), w2, a2[1]);
      a2[2] = __hfma2(u2h2(q2.z), w2, a2[2]); a2[3] = __hfma2(u2h2(q2.w), w2, a2[3]);
      a2[0] = __hfma2(u2h2(q3.x), w3, a2[0]); a2[1] = __hfma2(u2h2(q3.y), w3, a2[1]);
      a2[2] = __hfma2(u2h2(q3.z), w3, a2[2]); a2[3] = __hfma2(u2h2(q3.w), w3, a2[3]);
      a2[0] = __hfma2(u2h2(q4.x), w4, a2[0]); a2[1] = __hfma2(u2h2(q4.y), w4, a2[1]);
      a2[2] = __hfma2(u2h2(q4.z), w4, a2[2]); a2[3] = __hfma2(u2h2(q4.w), w4, a2[3]);
      a2[0] = __hfma2(u2h2(q5.x), w5, a2[0]); a2[1] = __hfma2(u2h2(q5.y), w5, a2[1]);
      a2[2] = __hfma2(u2h2(q5.z), w5, a2[2]); a2[3] = __hfma2(u2h2(q5.w), w5, a2[3]);
      a2[0] = __hfma2(u2h2(q6.x), w6, a2[0]); a2[1] = __hfma2(u2h2(q6.y), w6, a2[1]);
      a2[2] = __hfma2(u2h2(q6.z), w6, a2[2]); a2[3] = __hfma2(u2h2(q6.w), w6, a2[3]);
      a2[0] = __hfma2(u2h2(q7.x), w7, a2[0]); a2[1] = __hfma2(u2h2(q7.y), w7, a2[1]);
      a2[2] = __hfma2(u2h2(q7.z), w7, a2[2]); a2[3] = __hfma2(u2h2(q7.w), w7, a2[3]);
      *reinterpret_cast<uint4*>(&vals[wv][pl * 72 + gchg * 8]) =
          uint4{h22u(a2[0]), h22u(a2[1]), h22u(a2[2]), h22u(a2[3])};
    }
    // ---- MFMA: B-frag from this wave's own vals (same-wave ordering)
    {
      const unsigned short* wk = wTb + (size_t)k * 4096;
#pragma unroll
      for (int s = 0; s < 2; ++s) {
        half8 bfr = *reinterpret_cast<const half8*>(
            &vals[wv][posl * 72 + s * 32 + quad * 8]);
#pragma unroll
        for (int mt = 0; mt < 4; ++mt) {
          half8 afr = *reinterpret_cast<const half8*>(
              wk + mt * 1024 + s * 512 + posl * 32 + quad * 8);
          acc[mt] = __builtin_amdgcn_mfma_f32_16x16x32_f16(afr, bfr, acc[mt], 0, 0, 0);
        }
      }
    }
  }

  // part[kc][b][tile32][co][32] f16; co = mt*16+quad*4+reg, pos = wv*16+posl
  unsigned short* pp = part + ((size_t)(kc * 2 + b) * NT32 + tile) * 2048;
#pragma unroll
  for (int mt = 0; mt < 4; ++mt) {
#pragma unroll
    for (int reg = 0; reg < 4; ++reg) {
      int co = mt * 16 + quad * 4 + reg;
      pp[co * 32 + wv * 16 + posl] = f2h(acc[mt][reg]);
    }
  }
}

// out[b][co][p] = bias[co] + sum_kc part[kc][b][tile32][co][pos]  (f16 in, f32 out)
__global__ __launch_bounds__(256) void k_red(const unsigned short* __restrict__ part,
                                             const float* __restrict__ bias,
                                             float* __restrict__ out) {
  int i = blockIdx.x * 256 + threadIdx.x;  // 589,824 float4 units
  int p4 = i % (SP / 4);
  int co = (i / (SP / 4)) & 63;
  int b = i / ((SP / 4) * 64);
  int p = p4 * 4;
  int tile = p >> 5, pos = p & 31;
  size_t base = ((size_t)(b * NT32) + tile) * 2048 + co * 32 + pos;
  const __half2* h2 = (const __half2*)part;
  float bb = bias[co];
  float4 s = float4{bb, bb, bb, bb};
#pragma unroll
  for (int kc = 0; kc < KC; ++kc) {
    size_t e = (base + (size_t)kc * 2 * NT32 * 2048) >> 1;
    float2 a = __half22float2(h2[e]);
    float2 c = __half22float2(h2[e + 1]);
    s.x += a.x; s.y += a.y; s.z += c.x; s.w += c.y;
  }
  *reinterpret_cast<float4*>(&out[((size_t)(b * 64 + co)) * SP + p]) = s;
}

extern "C" void kernel_launch(void* const* d_in, const int* in_sizes, int n_in,
                              void* d_out, int out_size, void* d_ws, size_t ws_size,
                              hipStream_t stream) {
  const float* x = (const float*)d_in[0];
  const float* cw = (const float*)d_in[1];
  const float* cb = (const float*)d_in[2];
  const float* w = (const float*)d_in[3];
  const float* bias = (const float*)d_in[4];
  float* out = (float*)d_out;

  char* ws = (char*)d_ws;
  float* offT = (float*)ws;                                  // 15,925,248 B
  unsigned short* xTh = (unsigned short*)(ws + 15925248);    //  4,718,592 B
  unsigned short* wTb = (unsigned short*)(ws + 20643840);    //    221,184 B
  unsigned short* wq = (unsigned short*)(ws + 20865024);     //    331,776 B
  unsigned short* part = (unsigned short*)(ws + 21196800);   // 14,155,776 B (f16, 3 slices)
  unsigned short* opart = (unsigned short*)(ws + 35352576);  // 23,887,872 B (f16, 4 slices)

  hipLaunchKernelGGL(k_prep, dim3(10296), dim3(256), 0, stream, x, w, cw, xTh, wTb, wq);
  hipLaunchKernelGGL(k_offm3, dim3(TS * CS * 288), dim3(256), 0, stream, xTh, wq, opart);
  hipLaunchKernelGGL(k_offT, dim3(972), dim3(256), 0, stream, opart, cb, offT);
  hipLaunchKernelGGL(k_mainp, dim3(KC * 1152), dim3(128), 0, stream, xTh, offT, wTb, part);
  hipLaunchKernelGGL(k_red, dim3(2304), dim3(256), 0, stream, part, bias, out);
}

// Round 21
// 128.490 us; speedup vs baseline: 1.1801x; 1.0643x over previous
//
#include <hip/hip_runtime.h>
#include <hip/hip_fp16.h>

namespace {
constexpr int Bn = 2, Cin = 64, Cout = 64;
constexpr int Dd = 8, Hh = 48, Wd = 48;
constexpr int K = 27;
constexpr int SP = Dd * Hh * Wd;   // 18432
constexpr int PLANE = Hh * Wd;     // 2304
constexpr int NT32 = SP / 32;      // 576 32-pos tiles per batch
constexpr int KC = 3;              // K-split factor (main GEMM); KPER = 9
constexpr int KPER = K / KC;
constexpr int CS = 2;              // cin-split factor (offset conv)
constexpr int TS = 2;              // tap-split factor (offset conv)
}

typedef __attribute__((ext_vector_type(8))) _Float16 half8;
typedef __attribute__((ext_vector_type(4))) float f32x4;
typedef __attribute__((ext_vector_type(16))) float f32x16;

__device__ __forceinline__ unsigned short f2h(float f) {  // RNE float->f16 bits
  return __half_as_ushort(__float2half(f));
}
__device__ __forceinline__ __half2 u2h2(unsigned u) {
  return __builtin_bit_cast(__half2, u);
}
__device__ __forceinline__ unsigned h22u(__half2 h) {
  return __builtin_bit_cast(unsigned, h);
}

// Fused prep v2. Blocks 0..575: tiled x-transpose (64ch x 64pos LDS tile,
// coalesced reads AND writes — old version read with stride SP = 1 txn/elem).
// Blocks 576..1655: wTb + wq weight relayouts (element-indexed, tiny).
__global__ __launch_bounds__(256) void k_prep(const float* __restrict__ x,
                                              const float* __restrict__ w,
                                              const float* __restrict__ cw,
                                              unsigned short* __restrict__ xTh,
                                              unsigned short* __restrict__ wTb,
                                              unsigned short* __restrict__ wq) {
  __shared__ float tile[64 * 65];
  const int bid = blockIdx.x;
  const int t = threadIdx.x;
  if (bid < 576) {
    const int b = bid / 288;
    const int p0 = (bid - b * 288) * 64;
    const int lane = t & 63, grp = t >> 6;
    // phase 1: coalesced reads (wave spans 64 consecutive p of one channel)
#pragma unroll
    for (int cc = 0; cc < 16; ++cc) {
      int c = grp * 16 + cc;
      tile[c * 65 + lane] = x[((size_t)(b * 64 + c)) * SP + p0 + lane];
    }
    __syncthreads();
    // phase 2: coalesced writes (wave spans 64 channels of one position);
    // LDS read lane*65+pos -> all banks distinct, conflict-free
#pragma unroll
    for (int pp = 0; pp < 16; ++pp) {
      int pos = grp * 16 + pp;
      xTh[((size_t)(b * SP + p0 + pos)) * 64 + lane] = f2h(tile[lane * 65 + pos]);
    }
    return;
  }
  int i = (bid - 576) * 256 + t;            // 276,480 total
  if (i < 110592) {
    // wTb[k][mt(4)][s(2)][row(16)][kg(4)][j(8)]
    int j = i & 7, kg = (i >> 3) & 3, row = (i >> 5) & 15;
    int s = (i >> 9) & 1, mt = (i >> 10) & 3, k = i >> 12;
    int co = mt * 16 + row, cin = s * 32 + kg * 8 + j;
    wTb[i] = f2h(w[((size_t)co * Cin + cin) * K + k]);
  } else {
    // wq[tap][cs(2)][kh(2)][mt(3)][row(32)][ko(2)][j(8)]
    int i3 = i - 110592;                    // < 165,888
    int j = i3 & 7, ko = (i3 >> 3) & 1, row = (i3 >> 4) & 31;
    int qq = i3 >> 9;
    int mt = qq % 3;
    int rest = qq / 3;
    int kh = rest & 1;
    int cs = (rest >> 1) & 1;
    int tap = rest >> 2;
    int ch = mt * 32 + row, cin = cs * 32 + kh * 16 + ko * 8 + j;
    float v = (ch < 81) ? cw[((size_t)ch * 64 + cin) * 27 + tap] : 0.f;
    wq[i3] = f2h(v);
  }
}

// Offset conv via 32x32x16 MFMA (validated R18).
__global__ __launch_bounds__(256, 4) void k_offm3(const unsigned short* __restrict__ xTh,
                                                  const unsigned short* __restrict__ wq,
                                                  unsigned short* __restrict__ opart) {
  const int t = threadIdx.x;
  const int lane = t & 63;
  const int wv = t >> 6;                   // 0..3
  const int bid = blockIdx.x;              // slice*288 + nb ; 1152 total
  const int slice = bid / 288;             // ts*2 + cs
  const int nb = bid - slice * 288;
  const int ts = slice >> 1;
  const int cs = slice & 1;
  const int n0 = nb * 128;
  const int b = n0 / SP;
  const int sp0 = n0 - b * SP;

  const int col = lane & 31;
  const int ko = lane >> 5;
  const int q = sp0 + wv * 32 + col;
  const int d = q / PLANE;
  const int rp = q - d * PLANE;
  const int h = rp / 48;
  const int w = rp - h * 48;
  const int grow = b * SP + q;

  const char* xb8 = (const char*)xTh;
  const unsigned short* wbase = wq + cs * 3072 + col * 16 + ko * 8;
  const int bofs = cs * 64 + ko * 16;

  f32x16 acc[3];
#pragma unroll
  for (int mt = 0; mt < 3; ++mt)
#pragma unroll
    for (int r = 0; r < 16; ++r) acc[mt][r] = 0.f;

  const int t0 = ts * 14;
#pragma unroll
  for (int tt = 0; tt < 14; ++tt) {
    const int tap = t0 + tt;
    const bool tok = tap < 27;
    const int tap_c = tok ? tap : 26;
    const int kd = tap_c / 9, kh3 = (tap_c % 9) / 3, kw = tap_c % 3;
    const int dd = d + kd - 1, hh = h + kh3 - 1, ww = w + kw - 1;
    const bool valid = tok & ((unsigned)dd < 8u) & ((unsigned)hh < 48u) &
                       ((unsigned)ww < 48u);
    const int delta = (kd - 1) * PLANE + (kh3 - 1) * 48 + (kw - 1);
    int row = grow + delta;
    row = min(max(row, 0), Bn * SP - 1);
    const char* bp = xb8 + ((size_t)row << 7) + bofs;
    uint4 b0 = *reinterpret_cast<const uint4*>(bp);
    uint4 b1 = *reinterpret_cast<const uint4*>(bp + 32);
    const unsigned m = valid ? 0xFFFFFFFFu : 0u;
    b0.x &= m; b0.y &= m; b0.z &= m; b0.w &= m;
    b1.x &= m; b1.y &= m; b1.z &= m; b1.w &= m;
    half8 bf0 = __builtin_bit_cast(half8, b0);
    half8 bf1 = __builtin_bit_cast(half8, b1);
    const unsigned short* wt = wbase + tap_c * 6144;
#pragma unroll
    for (int mt = 0; mt < 3; ++mt) {
      half8 a0 = *reinterpret_cast<const half8*>(wt + mt * 512);
      acc[mt] = __builtin_amdgcn_mfma_f32_32x32x16_f16(a0, bf0, acc[mt], 0, 0, 0);
    }
#pragma unroll
    for (int mt = 0; mt < 3; ++mt) {
      half8 a1 = *reinterpret_cast<const half8*>(wt + 1536 + mt * 512);
      acc[mt] = __builtin_amdgcn_mfma_f32_32x32x16_f16(a1, bf1, acc[mt], 0, 0, 0);
    }
  }

  const int colp = sp0 + wv * 32 + col;
  unsigned short* pp = opart + (size_t)(slice * 2 + b) * 81 * SP;
#pragma unroll
  for (int mt = 0; mt < 3; ++mt) {
#pragma unroll
    for (int reg = 0; reg < 16; ++reg) {
      int ch = mt * 32 + (reg & 3) + 8 * (reg >> 2) + 4 * ko;
      if (ch < 81)
        pp[(size_t)ch * SP + colp] = f2h(acc[mt][reg]);
    }
  }
}

// offT[b][k][p] = float4(pd, ph, pw, 0), base grid + conv bias folded in;
// sums 4 f16 opart slices.
__global__ __launch_bounds__(256) void k_offT(const unsigned short* __restrict__ opart,
                                              const float* __restrict__ cb,
                                              float* __restrict__ offT) {
  int i = blockIdx.x * 256 + threadIdx.x;  // 2*27*4608 = 248,832
  int p4 = i % (SP / 4);
  int k = (i / (SP / 4)) % 27;
  int b = i / ((SP / 4) * 27);
  int kd = k / 9, kh = (k % 9) / 3, kw = k % 3;

  const __half2* op2 = (const __half2*)opart;
  float s[3][4];
#pragma unroll
  for (int dim = 0; dim < 3; ++dim) {
    int ch = dim * 27 + k;
    float bb = cb[ch];
    s[dim][0] = bb; s[dim][1] = bb; s[dim][2] = bb; s[dim][3] = bb;
#pragma unroll
    for (int sl = 0; sl < 4; ++sl) {
      size_t e0 = (((size_t)((sl * 2 + b) * 81 + ch)) * SP + p4 * 4) >> 1;
      float2 a0 = __half22float2(op2[e0]);
      float2 a1 = __half22float2(op2[e0 + 1]);
      s[dim][0] += a0.x; s[dim][1] += a0.y; s[dim][2] += a1.x; s[dim][3] += a1.y;
    }
  }
  float4* o4 = (float4*)offT + ((size_t)(b * 27 + k) * SP + p4 * 4);
#pragma unroll
  for (int e = 0; e < 4; ++e) {
    int p = p4 * 4 + e;
    int d = p / PLANE;
    int r = p - d * PLANE;
    int h = r / 48;
    int wp = r - h * 48;
    o4[e] = float4{s[0][e] + (float)(d + kd - 1), s[1][e] + (float)(h + kh - 1),
                   s[2][e] + (float)(wp + kw - 1), 0.f};
  }
}

// Fused gather + MFMA GEMM (R14 structure; f16 part; KC=3). Only change:
// launch_bounds (128,8)->(128,6): VGPR budget 64->85 so the 8 gather loads
// per unit can stay in flight (VGPR_Count was 28 -> ~4 serialized L2 trips);
// occupancy cap 24/CU ~= measured 21/CU, so no occupancy cost.
__global__ __launch_bounds__(128, 6) void k_mainp(const unsigned short* __restrict__ xTh,
                                                  const float* __restrict__ offT,
                                                  const unsigned short* __restrict__ wTb,
                                                  unsigned short* __restrict__ part) {
  __shared__ __align__(16) unsigned scp[2][16 * 20];         // per-wave [pos16][20w]
  __shared__ __align__(16) unsigned short vals[2][16 * 72];  // per-wave [pos16][cin]

  const int t = threadIdx.x;
  const int lane = t & 63;
  const int wv = t >> 6;                         // 0..1
  const int bid = blockIdx.x;                    // kc*1152 + j
  const int kc = bid / 1152;
  const int j = bid - kc * 1152;
  const int tl = (j & 7) * 144 + (j >> 3);       // XCD-contiguous tiles
  const int b = tl / NT32;
  const int tile = tl - b * NT32;
  const int p0 = tile * 32;

  const char* xb8 = (const char*)(xTh + (size_t)b * SP * 64);
  const float4* offTb = (const float4*)offT + (size_t)b * 27 * SP;

  const int posl = lane & 15;
  const int quad = lane >> 4;
  const int p = p0 + wv * 16 + posl;             // this lane's position
  unsigned* myrow = &scp[wv][posl * 20];

  const int gpl0 = lane >> 3;   // gather: row base 0..7
  const int gchg = lane & 7;    // gather: 8-channel chunk

  f32x4 acc[4];
#pragma unroll
  for (int mt = 0; mt < 4; ++mt) acc[mt] = f32x4{0.f, 0.f, 0.f, 0.f};

  for (int kk = 0; kk < KPER; ++kk) {
    const int k = kc * KPER + kk;
    // ---- setup: corners 2*quad, 2*quad+1 of position p (offT pre-folded)
    {
      float4 o = offTb[(size_t)k * SP + p];
      float df = floorf(o.x), hf = floorf(o.y), wf = floorf(o.z);
      float fd = o.x - df, fh = o.y - hf, fw = o.z - wf;
      int d0 = (int)df, h0 = (int)hf, w0i = (int)wf;
      unsigned pk[4];
#pragma unroll
      for (int cc = 0; cc < 2; ++cc) {
        int c = quad * 2 + cc;
        int cd = c >> 2, ch = (c >> 1) & 1, cwb = c & 1;
        int di = d0 + cd, hi = h0 + ch, wi = w0i + cwb;
        bool v = ((unsigned)di < 8u) && ((unsigned)hi < 48u) && ((unsigned)wi < 48u);
        float wg = (cd ? fd : 1.f - fd) * (ch ? fh : 1.f - fh) * (cwb ? fw : 1.f - fw);
        int dic = min(max(di, 0), 7), hic = min(max(hi, 0), 47), wic = min(max(wi, 0), 47);
        unsigned hs = (unsigned)f2h(v ? wg : 0.f);
        pk[cc * 2] = (unsigned)((dic * 48 + hic) * 48 + wic);
        pk[cc * 2 + 1] = hs | (hs << 16);
      }
      *reinterpret_cast<uint4*>(myrow + quad * 4) = uint4{pk[0], pk[1], pk[2], pk[3]};
    }
    // ---- gather: 2 units/lane, rows gpl0 and gpl0+8 (same-wave LDS ordering)
#pragma unroll
    for (int u = 0; u < 2; ++u) {
      const int pl = gpl0 + u * 8;
      const unsigned* sp = &scp[wv][pl * 20];
      const uint4 m0 = *reinterpret_cast<const uint4*>(sp + 0);
      const uint4 m1 = *reinterpret_cast<const uint4*>(sp + 4);
      const uint4 m2 = *reinterpret_cast<const uint4*>(sp + 8);
      const uint4 m3 = *reinterpret_cast<const uint4*>(sp + 12);
      const int cof = gchg << 4;
      uint4 q0 = *reinterpret_cast<const uint4*>(xb8 + (((size_t)m0.x << 7) + cof));
      uint4 q1 = *reinterpret_cast<const uint4*>(xb8 + (((size_t)m0.z << 7) + cof));
      uint4 q2 = *reinterpret_cast<const uint4*>(xb8 + (((size_t)m1.x << 7) + cof));
      uint4 q3 = *reinterpret_cast<const uint4*>(xb8 + (((size_t)m1.z << 7) + cof));
      uint4 q4 = *reinterpret_cast<const uint4*>(xb8 + (((size_t)m2.x << 7) + cof));
      uint4 q5 = *reinterpret_cast<const uint4*>(xb8 + (((size_t)m2.z << 7) + cof));
      uint4 q6 = *reinterpret_cast<const uint4*>(xb8 + (((size_t)m3.x << 7) + cof));
      uint4 q7 = *reinterpret_cast<const uint4*>(xb8 + (((size_t)m3.z << 7) + cof));
      __half2 a2[4];
#pragma unroll
      for (int e = 0; e < 4; ++e) a2[e] = u2h2(0u);
      __half2 w0 = u2h2(m0.y), w1 = u2h2(m0.w), w2 = u2h2(m1.y), w3 = u2h2(m1.w);
      __half2 w4 = u2h2(m2.y), w5 = u2h2(m2.w), w6 = u2h2(m3.y), w7 = u2h2(m3.w);
      a2[0] = __hfma2(u2h2(q0.x), w0, a2[0]); a2[1] = __hfma2(u2h2(q0.y), w0, a2[1]);
      a2[2] = __hfma2(u2h2(q0.z), w0, a2[2]); a2[3] = __hfma2(u2h2(q0.w), w0, a2[3]);
      a2[0] = __hfma2(u2h2(q1.x), w1, a2[0]); a2[1] = __hfma2(u2h2(q1.y), w1, a2[1]);
      a2[2] = __hfma2(u2h2(q1.z), w1, a2[2]); a2[3] = __hfma2(u2h2(q1.w), w1, a2[3]);
      a2[0] = __hfma2(u2h2(q2.x), w2, a2[0]); a2[1] = __hfma2(u2h2(q2.y), w2, a2[1]);
      a2[2] = __hfma2(u2h2(q2.z), w2, a2[2]); a2[3] = __hfma2(u2h2(q2.w), w2, a2[3]);
      a2[0] = __hfma2(u2h2(q3.x), w3, a2[0]); a2[1] = __hfma2(u2h2(q3.y), w3, a2[1]);
      a2[2] = __hfma2(u2h2(q3.z), w3, a2[2]); a2[3] = __hfma2(u2h2(q3.w), w3, a2[3]);
      a2[0] = __hfma2(u2h2(q4.x), w4, a2[0]); a2[1] = __hfma2(u2h2(q4.y), w4, a2[1]);
      a2[2] = __hfma2(u2h2(q4.z), w4, a2[2]); a2[3] = __hfma2(u2h2(q4.w), w4, a2[3]);
      a2[0] = __hfma2(u2h2(q5.x), w5, a2[0]); a2[1] = __hfma2(u2h2(q5.y), w5, a2[1]);
      a2[2] = __hfma2(u2h2(q5.z), w5, a2[2]); a2[3] = __hfma2(u2h2(q5.w), w5, a2[3]);
      a2[0] = __hfma2(u2h2(q6.x), w6, a2[0]); a2[1] = __hfma2(u2h2(q6.y), w6, a2[1]);
      a2[2] = __hfma2(u2h2(q6.z), w6, a2[2]); a2[3] = __hfma2(u2h2(q6.w), w6, a2[3]);
      a2[0] = __hfma2(u2h2(q7.x), w7, a2[0]); a2[1] = __hfma2(u2h2(q7.y), w7, a2[1]);
      a2[2] = __hfma2(u2h2(q7.z), w7, a2[2]); a2[3] = __hfma2(u2h2(q7.w), w7, a2[3]);
      *reinterpret_cast<uint4*>(&vals[wv][pl * 72 + gchg * 8]) =
          uint4{h22u(a2[0]), h22u(a2[1]), h22u(a2[2]), h22u(a2[3])};
    }
    // ---- MFMA: B-frag from this wave's own vals (same-wave ordering)
    {
      const unsigned short* wk = wTb + (size_t)k * 4096;
#pragma unroll
      for (int s = 0; s < 2; ++s) {
        half8 bfr = *reinterpret_cast<const half8*>(
            &vals[wv][posl * 72 + s * 32 + quad * 8]);
#pragma unroll
        for (int mt = 0; mt < 4; ++mt) {
          half8 afr = *reinterpret_cast<const half8*>(
              wk + mt * 1024 + s * 512 + posl * 32 + quad * 8);
          acc[mt] = __builtin_amdgcn_mfma_f32_16x16x32_f16(afr, bfr, acc[mt], 0, 0, 0);
        }
      }
    }
  }

  // part[kc][b][tile32][co][32] f16; co = mt*16+quad*4+reg, pos = wv*16+posl
  unsigned short* pp = part + ((size_t)(kc * 2 + b) * NT32 + tile) * 2048;
#pragma unroll
  for (int mt = 0; mt < 4; ++mt) {
#pragma unroll
    for (int reg = 0; reg < 4; ++reg) {
      int co = mt * 16 + quad * 4 + reg;
      pp[co * 32 + wv * 16 + posl] = f2h(acc[mt][reg]);
    }
  }
}

// out[b][co][p] = bias[co] + sum_kc part[kc][b][tile32][co][pos]  (f16 in, f32 out)
__global__ __launch_bounds__(256) void k_red(const unsigned short* __restrict__ part,
                                             const float* __restrict__ bias,
                                             float* __restrict__ out) {
  int i = blockIdx.x * 256 + threadIdx.x;  // 589,824 float4 units
  int p4 = i % (SP / 4);
  int co = (i / (SP / 4)) & 63;
  int b = i / ((SP / 4) * 64);
  int p = p4 * 4;
  int tile = p >> 5, pos = p & 31;
  size_t base = ((size_t)(b * NT32) + tile) * 2048 + co * 32 + pos;
  const __half2* h2 = (const __half2*)part;
  float bb = bias[co];
  float4 s = float4{bb, bb, bb, bb};
#pragma unroll
  for (int kc = 0; kc < KC; ++kc) {
    size_t e = (base + (size_t)kc * 2 * NT32 * 2048) >> 1;
    float2 a = __half22float2(h2[e]);
    float2 c = __half22float2(h2[e + 1]);
    s.x += a.x; s.y += a.y; s.z += c.x; s.w += c.y;
  }
  *reinterpret_cast<float4*>(&out[((size_t)(b * 64 + co)) * SP + p]) = s;
}

extern "C" void kernel_launch(void* const* d_in, const int* in_sizes, int n_in,
                              void* d_out, int out_size, void* d_ws, size_t ws_size,
                              hipStream_t stream) {
  const float* x = (const float*)d_in[0];
  const float* cw = (const float*)d_in[1];
  const float* cb = (const float*)d_in[2];
  const float* w = (const float*)d_in[3];
  const float* bias = (const float*)d_in[4];
  float* out = (float*)d_out;

  char* ws = (char*)d_ws;
  float* offT = (float*)ws;                                  // 15,925,248 B
  unsigned short* xTh = (unsigned short*)(ws + 15925248);    //  4,718,592 B
  unsigned short* wTb = (unsigned short*)(ws + 20643840);    //    221,184 B
  unsigned short* wq = (unsigned short*)(ws + 20865024);     //    331,776 B
  unsigned short* part = (unsigned short*)(ws + 21196800);   // 14,155,776 B (f16, 3 slices)
  unsigned short* opart = (unsigned short*)(ws + 35352576);  // 23,887,872 B (f16, 4 slices)

  hipLaunchKernelGGL(k_prep, dim3(1656), dim3(256), 0, stream, x, w, cw, xTh, wTb, wq);
  hipLaunchKernelGGL(k_offm3, dim3(TS * CS * 288), dim3(256), 0, stream, xTh, wq, opart);
  hipLaunchKernelGGL(k_offT, dim3(972), dim3(256), 0, stream, opart, cb, offT);
  hipLaunchKernelGGL(k_mainp, dim3(KC * 1152), dim3(128), 0, stream, xTh, offT, wTb, part);
  hipLaunchKernelGGL(k_red, dim3(2304), dim3(256), 0, stream, part, bias, out);
}

// Round 22
// 128.320 us; speedup vs baseline: 1.1817x; 1.0013x over previous
//
#include <hip/hip_runtime.h>
#include <hip/hip_fp16.h>

namespace {
constexpr int Bn = 2, Cin = 64, Cout = 64;
constexpr int Dd = 8, Hh = 48, Wd = 48;
constexpr int K = 27;
constexpr int SP = Dd * Hh * Wd;   // 18432
constexpr int PLANE = Hh * Wd;     // 2304
constexpr int NT32 = SP / 32;      // 576 32-pos tiles per batch
constexpr int KC = 3;              // K-split factor (main GEMM); KPER = 9
constexpr int KPER = K / KC;
constexpr int CS = 2;              // cin-split factor (offset conv)
constexpr int TS = 2;              // tap-split factor (offset conv)
}

typedef __attribute__((ext_vector_type(8))) _Float16 half8;
typedef __attribute__((ext_vector_type(4))) float f32x4;
typedef __attribute__((ext_vector_type(16))) float f32x16;

__device__ __forceinline__ unsigned short f2h(float f) {  // RNE float->f16 bits
  return __half_as_ushort(__float2half(f));
}
__device__ __forceinline__ __half2 u2h2(unsigned u) {
  return __builtin_bit_cast(__half2, u);
}
__device__ __forceinline__ unsigned h22u(__half2 h) {
  return __builtin_bit_cast(unsigned, h);
}

// Fused prep v2. Blocks 0..575: tiled x-transpose (64ch x 64pos LDS tile,
// coalesced reads AND writes — old version read with stride SP = 1 txn/elem).
// Blocks 576..1655: wTb + wq weight relayouts (element-indexed, tiny).
__global__ __launch_bounds__(256) void k_prep(const float* __restrict__ x,
                                              const float* __restrict__ w,
                                              const float* __restrict__ cw,
                                              unsigned short* __restrict__ xTh,
                                              unsigned short* __restrict__ wTb,
                                              unsigned short* __restrict__ wq) {
  __shared__ float tile[64 * 65];
  const int bid = blockIdx.x;
  const int t = threadIdx.x;
  if (bid < 576) {
    const int b = bid / 288;
    const int p0 = (bid - b * 288) * 64;
    const int lane = t & 63, grp = t >> 6;
    // phase 1: coalesced reads (wave spans 64 consecutive p of one channel)
#pragma unroll
    for (int cc = 0; cc < 16; ++cc) {
      int c = grp * 16 + cc;
      tile[c * 65 + lane] = x[((size_t)(b * 64 + c)) * SP + p0 + lane];
    }
    __syncthreads();
    // phase 2: coalesced writes (wave spans 64 channels of one position);
    // LDS read lane*65+pos -> all banks distinct, conflict-free
#pragma unroll
    for (int pp = 0; pp < 16; ++pp) {
      int pos = grp * 16 + pp;
      xTh[((size_t)(b * SP + p0 + pos)) * 64 + lane] = f2h(tile[lane * 65 + pos]);
    }
    return;
  }
  int i = (bid - 576) * 256 + t;            // 276,480 total
  if (i < 110592) {
    // wTb[k][mt(4)][s(2)][row(16)][kg(4)][j(8)]
    int j = i & 7, kg = (i >> 3) & 3, row = (i >> 5) & 15;
    int s = (i >> 9) & 1, mt = (i >> 10) & 3, k = i >> 12;
    int co = mt * 16 + row, cin = s * 32 + kg * 8 + j;
    wTb[i] = f2h(w[((size_t)co * Cin + cin) * K + k]);
  } else {
    // wq[tap][cs(2)][kh(2)][mt(3)][row(32)][ko(2)][j(8)]
    int i3 = i - 110592;                    // < 165,888
    int j = i3 & 7, ko = (i3 >> 3) & 1, row = (i3 >> 4) & 31;
    int qq = i3 >> 9;
    int mt = qq % 3;
    int rest = qq / 3;
    int kh = rest & 1;
    int cs = (rest >> 1) & 1;
    int tap = rest >> 2;
    int ch = mt * 32 + row, cin = cs * 32 + kh * 16 + ko * 8 + j;
    float v = (ch < 81) ? cw[((size_t)ch * 64 + cin) * 27 + tap] : 0.f;
    wq[i3] = f2h(v);
  }
}

// Offset conv via 32x32x16 MFMA (validated R18).
__global__ __launch_bounds__(256, 4) void k_offm3(const unsigned short* __restrict__ xTh,
                                                  const unsigned short* __restrict__ wq,
                                                  unsigned short* __restrict__ opart) {
  const int t = threadIdx.x;
  const int lane = t & 63;
  const int wv = t >> 6;                   // 0..3
  const int bid = blockIdx.x;              // slice*288 + nb ; 1152 total
  const int slice = bid / 288;             // ts*2 + cs
  const int nb = bid - slice * 288;
  const int ts = slice >> 1;
  const int cs = slice & 1;
  const int n0 = nb * 128;
  const int b = n0 / SP;
  const int sp0 = n0 - b * SP;

  const int col = lane & 31;
  const int ko = lane >> 5;
  const int q = sp0 + wv * 32 + col;
  const int d = q / PLANE;
  const int rp = q - d * PLANE;
  const int h = rp / 48;
  const int w = rp - h * 48;
  const int grow = b * SP + q;

  const char* xb8 = (const char*)xTh;
  const unsigned short* wbase = wq + cs * 3072 + col * 16 + ko * 8;
  const int bofs = cs * 64 + ko * 16;

  f32x16 acc[3];
#pragma unroll
  for (int mt = 0; mt < 3; ++mt)
#pragma unroll
    for (int r = 0; r < 16; ++r) acc[mt][r] = 0.f;

  const int t0 = ts * 14;
#pragma unroll
  for (int tt = 0; tt < 14; ++tt) {
    const int tap = t0 + tt;
    const bool tok = tap < 27;
    const int tap_c = tok ? tap : 26;
    const int kd = tap_c / 9, kh3 = (tap_c % 9) / 3, kw = tap_c % 3;
    const int dd = d + kd - 1, hh = h + kh3 - 1, ww = w + kw - 1;
    const bool valid = tok & ((unsigned)dd < 8u) & ((unsigned)hh < 48u) &
                       ((unsigned)ww < 48u);
    const int delta = (kd - 1) * PLANE + (kh3 - 1) * 48 + (kw - 1);
    int row = grow + delta;
    row = min(max(row, 0), Bn * SP - 1);
    const char* bp = xb8 + ((size_t)row << 7) + bofs;
    uint4 b0 = *reinterpret_cast<const uint4*>(bp);
    uint4 b1 = *reinterpret_cast<const uint4*>(bp + 32);
    const unsigned m = valid ? 0xFFFFFFFFu : 0u;
    b0.x &= m; b0.y &= m; b0.z &= m; b0.w &= m;
    b1.x &= m; b1.y &= m; b1.z &= m; b1.w &= m;
    half8 bf0 = __builtin_bit_cast(half8, b0);
    half8 bf1 = __builtin_bit_cast(half8, b1);
    const unsigned short* wt = wbase + tap_c * 6144;
#pragma unroll
    for (int mt = 0; mt < 3; ++mt) {
      half8 a0 = *reinterpret_cast<const half8*>(wt + mt * 512);
      acc[mt] = __builtin_amdgcn_mfma_f32_32x32x16_f16(a0, bf0, acc[mt], 0, 0, 0);
    }
#pragma unroll
    for (int mt = 0; mt < 3; ++mt) {
      half8 a1 = *reinterpret_cast<const half8*>(wt + 1536 + mt * 512);
      acc[mt] = __builtin_amdgcn_mfma_f32_32x32x16_f16(a1, bf1, acc[mt], 0, 0, 0);
    }
  }

  const int colp = sp0 + wv * 32 + col;
  unsigned short* pp = opart + (size_t)(slice * 2 + b) * 81 * SP;
#pragma unroll
  for (int mt = 0; mt < 3; ++mt) {
#pragma unroll
    for (int reg = 0; reg < 16; ++reg) {
      int ch = mt * 32 + (reg & 3) + 8 * (reg >> 2) + 4 * ko;
      if (ch < 81)
        pp[(size_t)ch * SP + colp] = f2h(acc[mt][reg]);
    }
  }
}

// offT[b][k][p] = float4(pd, ph, pw, 0), base grid + conv bias folded in;
// sums 4 f16 opart slices.
__global__ __launch_bounds__(256) void k_offT(const unsigned short* __restrict__ opart,
                                              const float* __restrict__ cb,
                                              float* __restrict__ offT) {
  int i = blockIdx.x * 256 + threadIdx.x;  // 2*27*4608 = 248,832
  int p4 = i % (SP / 4);
  int k = (i / (SP / 4)) % 27;
  int b = i / ((SP / 4) * 27);
  int kd = k / 9, kh = (k % 9) / 3, kw = k % 3;

  const __half2* op2 = (const __half2*)opart;
  float s[3][4];
#pragma unroll
  for (int dim = 0; dim < 3; ++dim) {
    int ch = dim * 27 + k;
    float bb = cb[ch];
    s[dim][0] = bb; s[dim][1] = bb; s[dim][2] = bb; s[dim][3] = bb;
#pragma unroll
    for (int sl = 0; sl < 4; ++sl) {
      size_t e0 = (((size_t)((sl * 2 + b) * 81 + ch)) * SP + p4 * 4) >> 1;
      float2 a0 = __half22float2(op2[e0]);
      float2 a1 = __half22float2(op2[e0 + 1]);
      s[dim][0] += a0.x; s[dim][1] += a0.y; s[dim][2] += a1.x; s[dim][3] += a1.y;
    }
  }
  float4* o4 = (float4*)offT + ((size_t)(b * 27 + k) * SP + p4 * 4);
#pragma unroll
  for (int e = 0; e < 4; ++e) {
    int p = p4 * 4 + e;
    int d = p / PLANE;
    int r = p - d * PLANE;
    int h = r / 48;
    int wp = r - h * 48;
    o4[e] = float4{s[0][e] + (float)(d + kd - 1), s[1][e] + (float)(h + kh - 1),
                   s[2][e] + (float)(wp + kw - 1), 0.f};
  }
}

// Fused gather + MFMA GEMM (R14 structure; f16 part; KC=3). Only change:
// launch_bounds (128,8)->(128,6): VGPR budget 64->85 so the 8 gather loads
// per unit can stay in flight (VGPR_Count was 28 -> ~4 serialized L2 trips);
// occupancy cap 24/CU ~= measured 21/CU, so no occupancy cost.
__global__ __launch_bounds__(128, 6) void k_mainp(const unsigned short* __restrict__ xTh,
                                                  const float* __restrict__ offT,
                                                  const unsigned short* __restrict__ wTb,
                                                  unsigned short* __restrict__ part) {
  __shared__ __align__(16) unsigned scp[2][16 * 20];         // per-wave [pos16][20w]
  __shared__ __align__(16) unsigned short vals[2][16 * 72];  // per-wave [pos16][cin]

  const int t = threadIdx.x;
  const int lane = t & 63;
  const int wv = t >> 6;                         // 0..1
  const int bid = blockIdx.x;                    // kc*1152 + j
  const int kc = bid / 1152;
  const int j = bid - kc * 1152;
  const int tl = (j & 7) * 144 + (j >> 3);       // XCD-contiguous tiles
  const int b = tl / NT32;
  const int tile = tl - b * NT32;
  const int p0 = tile * 32;

  const char* xb8 = (const char*)(xTh + (size_t)b * SP * 64);
  const float4* offTb = (const float4*)offT + (size_t)b * 27 * SP;

  const int posl = lane & 15;
  const int quad = lane >> 4;
  const int p = p0 + wv * 16 + posl;             // this lane's position
  unsigned* myrow = &scp[wv][posl * 20];

  const int gpl0 = lane >> 3;   // gather: row base 0..7
  const int gchg = lane & 7;    // gather: 8-channel chunk

  f32x4 acc[4];
#pragma unroll
  for (int mt = 0; mt < 4; ++mt) acc[mt] = f32x4{0.f, 0.f, 0.f, 0.f};

  for (int kk = 0; kk < KPER; ++kk) {
    const int k = kc * KPER + kk;
    // ---- setup: corners 2*quad, 2*quad+1 of position p (offT pre-folded)
    {
      float4 o = offTb[(size_t)k * SP + p];
      float df = floorf(o.x), hf = floorf(o.y), wf = floorf(o.z);
      float fd = o.x - df, fh = o.y - hf, fw = o.z - wf;
      int d0 = (int)df, h0 = (int)hf, w0i = (int)wf;
      unsigned pk[4];
#pragma unroll
      for (int cc = 0; cc < 2; ++cc) {
        int c = quad * 2 + cc;
        int cd = c >> 2, ch = (c >> 1) & 1, cwb = c & 1;
        int di = d0 + cd, hi = h0 + ch, wi = w0i + cwb;
        bool v = ((unsigned)di < 8u) && ((unsigned)hi < 48u) && ((unsigned)wi < 48u);
        float wg = (cd ? fd : 1.f - fd) * (ch ? fh : 1.f - fh) * (cwb ? fw : 1.f - fw);
        int dic = min(max(di, 0), 7), hic = min(max(hi, 0), 47), wic = min(max(wi, 0), 47);
        unsigned hs = (unsigned)f2h(v ? wg : 0.f);
        pk[cc * 2] = (unsigned)((dic * 48 + hic) * 48 + wic);
        pk[cc * 2 + 1] = hs | (hs << 16);
      }
      *reinterpret_cast<uint4*>(myrow + quad * 4) = uint4{pk[0], pk[1], pk[2], pk[3]};
    }
    // ---- gather: 2 units/lane, rows gpl0 and gpl0+8 (same-wave LDS ordering)
#pragma unroll
    for (int u = 0; u < 2; ++u) {
      const int pl = gpl0 + u * 8;
      const unsigned* sp = &scp[wv][pl * 20];
      const uint4 m0 = *reinterpret_cast<const uint4*>(sp + 0);
      const uint4 m1 = *reinterpret_cast<const uint4*>(sp + 4);
      const uint4 m2 = *reinterpret_cast<const uint4*>(sp + 8);
      const uint4 m3 = *reinterpret_cast<const uint4*>(sp + 12);
      const int cof = gchg << 4;
      uint4 q0 = *reinterpret_cast<const uint4*>(xb8 + (((size_t)m0.x << 7) + cof));
      uint4 q1 = *reinterpret_cast<const uint4*>(xb8 + (((size_t)m0.z << 7) + cof));
      uint4 q2 = *reinterpret_cast<const uint4*>(xb8 + (((size_t)m1.x << 7) + cof));
      uint4 q3 = *reinterpret_cast<const uint4*>(xb8 + (((size_t)m1.z << 7) + cof));
      uint4 q4 = *reinterpret_cast<const uint4*>(xb8 + (((size_t)m2.x << 7) + cof));
      uint4 q5 = *reinterpret_cast<const uint4*>(xb8 + (((size_t)m2.z << 7) + cof));
      uint4 q6 = *reinterpret_cast<const uint4*>(xb8 + (((size_t)m3.x << 7) + cof));
      uint4 q7 = *reinterpret_cast<const uint4*>(xb8 + (((size_t)m3.z << 7) + cof));
      __half2 a2[4];
#pragma unroll
      for (int e = 0; e < 4; ++e) a2[e] = u2h2(0u);
      __half2 w0 = u2h2(m0.y), w1 = u2h2(m0.w), w2 = u2h2(m1.y), w3 = u2h2(m1.w);
      __half2 w4 = u2h2(m2.y), w5 = u2h2(m2.w), w6 = u2h2(m3.y), w7 = u2h2(m3.w);
      a2[0] = __hfma2(u2h2(q0.x), w0, a2[0]); a2[1] = __hfma2(u2h2(q0.y), w0, a2[1]);
      a2[2] = __hfma2(u2h2(q0.z), w0, a2[2]); a2[3] = __hfma2(u2h2(q0.w), w0, a2[3]);
      a2[0] = __hfma2(u2h2(q1.x), w1, a2[0]); a2[1] = __hfma2(u2h2(q1.y), w1, a2[1]);
      a2[2] = __hfma2(u2h2(q1.z), w1, a2[2]); a2[3] = __hfma2(u2h2(q1.w), w1, a2[3]);
      a2[0] = __hfma2(u2h2(q2.x), w2, a2[0]); a2[1] = __hfma2(u2h2(q2.y), w2, a2[1]);
      a2[2] = __hfma2(u2h2(q2.z), w2, a2[2]); a2[3] = __hfma2(u2h2(q2.w), w2, a2[3]);
      a2[0] = __hfma2(u2h2(q3.x), w3, a2[0]); a2[1] = __hfma2(u2h2(q3.y), w3, a2[1]);
      a2[2] = __hfma2(u2h2(q3.z), w3, a2[2]); a2[3] = __hfma2(u2h2(q3.w), w3, a2[3]);
      a2[0] = __hfma2(u2h2(q4.x), w4, a2[0]); a2[1] = __hfma2(u2h2(q4.y), w4, a2[1]);
      a2[2] = __hfma2(u2h2(q4.z), w4, a2[2]); a2[3] = __hfma2(u2h2(q4.w), w4, a2[3]);
      a2[0] = __hfma2(u2h2(q5.x), w5, a2[0]); a2[1] = __hfma2(u2h2(q5.y), w5, a2[1]);
      a2[2] = __hfma2(u2h2(q5.z), w5, a2[2]); a2[3] = __hfma2(u2h2(q5.w), w5, a2[3]);
      a2[0] = __hfma2(u2h2(q6.x), w6, a2[0]); a2[1] = __hfma2(u2h2(q6.y), w6, a2[1]);
      a2[2] = __hfma2(u2h2(q6.z), w6, a2[2]); a2[3] = __hfma2(u2h2(q6.w), w6, a2[3]);
      a2[0] = __hfma2(u2h2(q7.x), w7, a2[0]); a2[1] = __hfma2(u2h2(q7.y), w7, a2[1]);
      a2[2] = __hfma2(u2h2(q7.z), w7, a2[2]); a2[3] = __hfma2(u2h2(q7.w), w7, a2[3]);
      *reinterpret_cast<uint4*>(&vals[wv][pl * 72 + gchg * 8]) =
          uint4{h22u(a2[0]), h22u(a2[1]), h22u(a2[2]), h22u(a2[3])};
    }
    // ---- MFMA: B-frag from this wave's own vals (same-wave ordering)
    {
      const unsigned short* wk = wTb + (size_t)k * 4096;
#pragma unroll
      for (int s = 0; s < 2; ++s) {
        half8 bfr = *reinterpret_cast<const half8*>(
            &vals[wv][posl * 72 + s * 32 + quad * 8]);
#pragma unroll
        for (int mt = 0; mt < 4; ++mt) {
          half8 afr = *reinterpret_cast<const half8*>(
              wk + mt * 1024 + s * 512 + posl * 32 + quad * 8);
          acc[mt] = __builtin_amdgcn_mfma_f32_16x16x32_f16(afr, bfr, acc[mt], 0, 0, 0);
        }
      }
    }
  }

  // part[kc][b][tile32][co][32] f16; co = mt*16+quad*4+reg, pos = wv*16+posl
  unsigned short* pp = part + ((size_t)(kc * 2 + b) * NT32 + tile) * 2048;
#pragma unroll
  for (int mt = 0; mt < 4; ++mt) {
#pragma unroll
    for (int reg = 0; reg < 4; ++reg) {
      int co = mt * 16 + quad * 4 + reg;
      pp[co * 32 + wv * 16 + posl] = f2h(acc[mt][reg]);
    }
  }
}

// out[b][co][p] = bias[co] + sum_kc part[kc][b][tile32][co][pos]  (f16 in, f32 out)
__global__ __launch_bounds__(256) void k_red(const unsigned short* __restrict__ part,
                                             const float* __restrict__ bias,
                                             float* __restrict__ out) {
  int i = blockIdx.x * 256 + threadIdx.x;  // 589,824 float4 units
  int p4 = i % (SP / 4);
  int co = (i / (SP / 4)) & 63;
  int b = i / ((SP / 4) * 64);
  int p = p4 * 4;
  int tile = p >> 5, pos = p & 31;
  size_t base = ((size_t)(b * NT32) + tile) * 2048 + co * 32 + pos;
  const __half2* h2 = (const __half2*)part;
  float bb = bias[co];
  float4 s = float4{bb, bb, bb, bb};
#pragma unroll
  for (int kc = 0; kc < KC; ++kc) {
    size_t e = (base + (size_t)kc * 2 * NT32 * 2048) >> 1;
    float2 a = __half22float2(h2[e]);
    float2 c = __half22float2(h2[e + 1]);
    s.x += a.x; s.y += a.y; s.z += c.x; s.w += c.y;
  }
  *reinterpret_cast<float4*>(&out[((size_t)(b * 64 + co)) * SP + p]) = s;
}

extern "C" void kernel_launch(void* const* d_in, const int* in_sizes, int n_in,
                              void* d_out, int out_size, void* d_ws, size_t ws_size,
                              hipStream_t stream) {
  const float* x = (const float*)d_in[0];
  const float* cw = (const float*)d_in[1];
  const float* cb = (const float*)d_in[2];
  const float* w = (const float*)d_in[3];
  const float* bias = (const float*)d_in[4];
  float* out = (float*)d_out;

  char* ws = (char*)d_ws;
  float* offT = (float*)ws;                                  // 15,925,248 B
  unsigned short* xTh = (unsigned short*)(ws + 15925248);    //  4,718,592 B
  unsigned short* wTb = (unsigned short*)(ws + 20643840);    //    221,184 B
  unsigned short* wq = (unsigned short*)(ws + 20865024);     //    331,776 B
  unsigned short* part = (unsigned short*)(ws + 21196800);   // 14,155,776 B (f16, 3 slices)
  unsigned short* opart = (unsigned short*)(ws + 35352576);  // 23,887,872 B (f16, 4 slices)

  hipLaunchKernelGGL(k_prep, dim3(1656), dim3(256), 0, stream, x, w, cw, xTh, wTb, wq);
  hipLaunchKernelGGL(k_offm3, dim3(TS * CS * 288), dim3(256), 0, stream, xTh, wq, opart);
  hipLaunchKernelGGL(k_offT, dim3(972), dim3(256), 0, stream, opart, cb, offT);
  hipLaunchKernelGGL(k_mainp, dim3(KC * 1152), dim3(128), 0, stream, xTh, offT, wTb, part);
  hipLaunchKernelGGL(k_red, dim3(2304), dim3(256), 0, stream, part, bias, out);
}